// Round 14
// baseline (551.935 us; speedup 1.0000x reference)
//
#include <hip/hip_runtime.h>

typedef unsigned short u16;
typedef unsigned int   u32;

using sx8    = __attribute__((ext_vector_type(8))) short;   // 8 x bf16 bits
using f32x4  = __attribute__((ext_vector_type(4))) float;
using f32x16 = __attribute__((ext_vector_type(16))) float;
using u16x8  = __attribute__((ext_vector_type(8))) unsigned short;

#define BB 4
#define TT 2048
#define CC 2048
#define HH 16
#define DD 128
#define FF 6144
#define MM 8192

static __device__ __forceinline__ u16 f2bf(float f) {
    u32 u = __builtin_bit_cast(u32, f);
    u32 lsb = (u >> 16) & 1u;
    u += 0x7fffu + lsb;
    return (u16)(u >> 16);
}
static __device__ __forceinline__ float bf2f(u16 b) {
    return __builtin_bit_cast(float, (u32)b << 16);
}
static __device__ __forceinline__ f32x4 mfma16(sx8 a, sx8 b, f32x4 c) {
    return __builtin_amdgcn_mfma_f32_16x16x32_bf16(a, b, c, 0, 0, 0);
}
static __device__ __forceinline__ f32x16 mfma32(sx8 a, sx8 b, f32x16 c) {
    return __builtin_amdgcn_mfma_f32_32x32x16_bf16(a, b, c, 0, 0, 0);
}
static __device__ __forceinline__ u32 pkbf(float a, float b) {
    return (u32)f2bf(a) | ((u32)f2bf(b) << 16);
}

// ---------------- fused f32 -> bf16 convert for x, w_qkv, w_out ----------------
// destinations are contiguous in workspace: [xb | wqb | wob]
__global__ __launch_bounds__(256) void k_cvt3(const float* __restrict__ x,
                                              const float* __restrict__ wq,
                                              const float* __restrict__ wo,
                                              u16* __restrict__ dst) {
    const size_t n0 = (size_t)MM * CC / 8, n1 = n0 + (size_t)FF * CC / 8;
    const size_t n2 = n1 + (size_t)CC * CC / 8;
    size_t i = (size_t)blockIdx.x * 256 + threadIdx.x;
    if (i >= n2) return;
    const float* s;
    size_t off;
    if (i < n0)      { s = x;  off = i; }
    else if (i < n1) { s = wq; off = i - n0; }
    else             { s = wo; off = i - n1; }
    const float4* sp = (const float4*)s;
    float4 a = sp[2 * off], b = sp[2 * off + 1];
    u16x8 r;
    r[0] = f2bf(a.x); r[1] = f2bf(a.y); r[2] = f2bf(a.z); r[3] = f2bf(a.w);
    r[4] = f2bf(b.x); r[5] = f2bf(b.y); r[6] = f2bf(b.z); r[7] = f2bf(b.w);
    *(u16x8*)(dst + 8 * i) = r;
}

// ---------------- bf16 A(MxK) @ Bt(NxK)^T GEMM, m97 structure, 32x32x16 MFMA ----------------
// Wave tile 64x64 = 2x2 of 32x32. A/B frag: row|col = l&31, k = (l>>5)*8+j.
// C/D: col = lane&31, row = (reg&3) + 8*(reg>>2) + 4*(lane>>5)  [m74/m101].
// MODE 1: plain f32 C output (out-proj).
// MODE 2: fused epilogue — RoPE(Q,K) + QKV split + V transpose.
template <int MODE>
__global__ __launch_bounds__(256, 2) void k_gemm(const u16* __restrict__ A,
                                                 const u16* __restrict__ Bt,
                                                 float* __restrict__ Cf,
                                                 const float* __restrict__ freqs,
                                                 u16* __restrict__ Qo,
                                                 u16* __restrict__ Ko,
                                                 u16* __restrict__ Vt,
                                                 int M, int N, int K) {
    __shared__ __align__(16) u16 sA[128 * 32];
    __shared__ __align__(16) u16 sB[128 * 32];
    __shared__ __align__(16) u16 vT[4][64][33];     // MODE 2 V-transpose staging
    const int n0 = blockIdx.x * 128, m0 = blockIdx.y * 128;
    const int tid = threadIdx.x, w = tid >> 6, l = tid & 63;
    const int wm = w >> 1, wn = w & 1;
    const int l31 = l & 31, hi = l >> 5;
    f32x16 acc[2][2] = {};

    const int idx0 = w * 128 + l;
    const int idx1 = idx0 + 64;
    const int ra0 = idx0 >> 2, ca0 = (idx0 & 3) * 8;
    const int ra1 = idx1 >> 2, ca1 = (idx1 & 3) * 8;
    const u16* Ar0 = A + (size_t)(m0 + ra0) * K + ca0;
    const u16* Ar1 = A + (size_t)(m0 + ra1) * K + ca1;
    const u16* Br0 = Bt + (size_t)(n0 + ra0) * K + ca0;
    const u16* Br1 = Bt + (size_t)(n0 + ra1) * K + ca1;
    u16* sAd0 = sA + (w * 2 + 0) * 512;
    u16* sAd1 = sA + (w * 2 + 1) * 512;
    u16* sBd0 = sB + (w * 2 + 0) * 512;
    u16* sBd1 = sB + (w * 2 + 1) * 512;

    for (int k0 = 0; k0 < K; k0 += 32) {
        __builtin_amdgcn_global_load_lds(
            (const __attribute__((address_space(1))) void*)(Ar0 + k0),
            (__attribute__((address_space(3))) void*)sAd0, 16, 0, 0);
        __builtin_amdgcn_global_load_lds(
            (const __attribute__((address_space(1))) void*)(Ar1 + k0),
            (__attribute__((address_space(3))) void*)sAd1, 16, 0, 0);
        __builtin_amdgcn_global_load_lds(
            (const __attribute__((address_space(1))) void*)(Br0 + k0),
            (__attribute__((address_space(3))) void*)sBd0, 16, 0, 0);
        __builtin_amdgcn_global_load_lds(
            (const __attribute__((address_space(1))) void*)(Br1 + k0),
            (__attribute__((address_space(3))) void*)sBd1, 16, 0, 0);
        __syncthreads();
        sx8 af[2][2], bfr[2][2];    // [tile][k-step]
#pragma unroll
        for (int ti = 0; ti < 2; ++ti)
#pragma unroll
            for (int ks = 0; ks < 2; ++ks) {
                af[ti][ks]  = *(const sx8*)(sA + (wm * 64 + ti * 32 + l31) * 32 + ks * 16 + hi * 8);
                bfr[ti][ks] = *(const sx8*)(sB + (wn * 64 + ti * 32 + l31) * 32 + ks * 16 + hi * 8);
            }
#pragma unroll
        for (int ks = 0; ks < 2; ++ks)
#pragma unroll
            for (int ti = 0; ti < 2; ++ti)
#pragma unroll
                for (int tj = 0; tj < 2; ++tj)
                    acc[ti][tj] = mfma32(af[ti][ks], bfr[tj][ks], acc[ti][tj]);
        __syncthreads();
    }

    if (MODE == 1) {
        // plain f32 epilogue
#pragma unroll
        for (int ti = 0; ti < 2; ++ti)
#pragma unroll
            for (int tj = 0; tj < 2; ++tj) {
                const int nc = n0 + wn * 64 + tj * 32 + l31;
#pragma unroll
                for (int r = 0; r < 16; ++r) {
                    const int mr = m0 + wm * 64 + ti * 32 + (r & 3) + 8 * (r >> 2) + 4 * hi;
                    Cf[(size_t)mr * N + nc] = acc[ti][tj][r];
                }
            }
    } else {
        // fused qkv epilogue
        const int b = m0 >> 11;                 // batch (block-uniform)
        const int t0blk = m0 & 2047;
        const int kind = n0 >> 11;              // 0=Q 1=K 2=V (block-uniform)
        const int h = (n0 & 2047) >> 7;         // head (block-uniform)
        const size_t bh = (size_t)(b * HH + h);
        if (kind < 2) {
            u16* dst = (kind == 0 ? Qo : Ko) + bh * (size_t)(TT * DD);
            const float qs = (kind == 0) ? 0.08838834764831845f : 1.0f;
#pragma unroll
            for (int ti = 0; ti < 2; ++ti)
#pragma unroll
                for (int tj = 0; tj < 2; ++tj) {
                    const int d = wn * 64 + tj * 32 + l31;     // 0..127, lane parity = d parity
                    const int dp2 = (d >> 1) * 2;
#pragma unroll
                    for (int r = 0; r < 16; ++r) {
                        const int t = t0blk + wm * 64 + ti * 32 + (r & 3) + 8 * (r >> 2) + 4 * hi;
                        float v = acc[ti][tj][r];
                        float p = __shfl_xor(v, 1);
                        float2 cs = *(const float2*)(freqs + (size_t)t * DD + dp2);
                        float rr = (l & 1) ? (p * cs.y + v * cs.x)
                                           : (v * cs.x - p * cs.y);
                        dst[(size_t)t * DD + d] = f2bf(rr * qs);
                    }
                }
        } else {
            u16* dstV = Vt + bh * (size_t)(DD * TT);
            const int t0w = t0blk + wm * 64;
            const int dl = l >> 1, seg = l & 1;
#pragma unroll
            for (int tj = 0; tj < 2; ++tj) {
#pragma unroll
                for (int ti = 0; ti < 2; ++ti)
#pragma unroll
                    for (int r = 0; r < 16; ++r)
                        vT[w][ti * 32 + (r & 3) + 8 * (r >> 2) + 4 * hi][l31] =
                            f2bf(acc[ti][tj][r]);
                asm volatile("s_waitcnt lgkmcnt(0)" ::: "memory");
                __builtin_amdgcn_sched_barrier(0);
                const int dg = wn * 64 + tj * 32 + dl;
                u16* orow = dstV + (size_t)dg * TT + t0w + seg * 32;
#pragma unroll
                for (int half = 0; half < 4; ++half) {
                    u16x8 t2;
#pragma unroll
                    for (int jj = 0; jj < 8; ++jj)
                        t2[jj] = vT[w][seg * 32 + half * 8 + jj][dl];
                    *(u16x8*)(orow + half * 8) = t2;
                }
                asm volatile("s_waitcnt lgkmcnt(0)" ::: "memory");   // reads done before next tj overwrites
                __builtin_amdgcn_sched_barrier(0);
            }
        }
    }
}

// ---------------- causal flash attention: 4 waves x 32 q-rows, KVBLK=64 ----------------
// Round-5 schedule (512 uniform blocks, strip-pair (x,15-x), 2-phase dbuf K staging)
// + swapped QK^T: S^T = mfma(K,Q) puts each q-row's scores lane-local
//   (row = lane&15, 16 k-vals in regs) -> in-reg reduce + 2 shfl_xor, packed b64 P writes.
#define KV 64
#define PST 68

__global__ __launch_bounds__(256, 2) void k_attn(const u16* __restrict__ Q,
                                                 const u16* __restrict__ K,
                                                 const u16* __restrict__ Vt,
                                                 u16* __restrict__ AO) {
    const int fid = blockIdx.x + 8 * blockIdx.y + 128 * blockIdx.z;
    const int xg = fid >> 6;                // 0..7  (strip-pair index)
    const int hb = fid & 63;
    const int h = hb & 15, b = hb >> 4;

    const int tid = threadIdx.x, w = tid >> 6, l = tid & 63;
    const int lr = l & 15, lg = l >> 4;
    const size_t bh = (size_t)(b * HH + h);
    const u16* Qh = Q + bh * TT * DD;
    const u16* Kh = K + bh * TT * DD;
    const u16* Vh = Vt + bh * DD * TT;

    __shared__ __align__(16) u16 sK[2][KV * DD];    // 32 KB, double-buffered, XOR-swizzled
    __shared__ __align__(16) u16 sP[4][32 * PST];   // 17 KB, per-wave P tiles
    u16* myP = sP[w];

    const int strow = tid >> 4;       // staging sub-row 0..15
    const int sc16  = tid & 15;       // staging 16B-column

    for (int rep = 0; rep < 2; ++rep) {
        const int g = rep ? (15 - xg) : xg;     // strip-group (128 rows)
        const int q0w = g * 128 + w * 32;       // this wave's first q row
        const int nt = 2 * g + 2;               // k-tiles of 64

        sx8 qf[2][4];
#pragma unroll
        for (int i = 0; i < 2; i++)
#pragma unroll
            for (int kk = 0; kk < 4; kk++)
                qf[i][kk] = *(const sx8*)(Qh + (size_t)(q0w + i * 16 + lr) * DD + kk * 32 + lg * 8);

        f32x4 o[2][8] = {};
        float mrow[2] = {-1e30f, -1e30f};
        float lrow[2] = {0.0f, 0.0f};

        // prologue: stage tile 0 into buf 0 (linear dest, inverse-swizzled source)
#pragma unroll
        for (int i = 0; i < 4; ++i) {
            const int row = i * 16 + strow;
            const int scol = (sc16 ^ (row & 7)) * 8;
            __builtin_amdgcn_global_load_lds(
                (const __attribute__((address_space(1))) void*)(Kh + (size_t)row * DD + scol),
                (__attribute__((address_space(3))) void*)(&sK[0][i * 2048 + w * 512]),
                16, 0, 0);
        }
        __syncthreads();

        int cur = 0;
        for (int t = 0; t < nt; ++t) {
            const int k0 = t * KV;
            if (t + 1 < nt) {               // prefetch next K tile into buf^1
                const int kn = k0 + KV;
#pragma unroll
                for (int i = 0; i < 4; ++i) {
                    const int row = i * 16 + strow;
                    const int scol = (sc16 ^ (row & 7)) * 8;
                    __builtin_amdgcn_global_load_lds(
                        (const __attribute__((address_space(1))) void*)(Kh + (size_t)(kn + row) * DD + scol),
                        (__attribute__((address_space(3))) void*)(&sK[cur ^ 1][i * 2048 + w * 512]),
                        16, 0, 0);
                }
            }
            if (k0 <= q0w) {                // causally active for this wave
                // ---- S^T = K·Q^T from swizzled LDS: k on (lg,rg), q-row on lr ----
                f32x4 st[2][4] = {};
#pragma unroll
                for (int j = 0; j < 4; ++j) {
                    const int row = j * 16 + lr;
                    const int rx = row & 7;
                    sx8 kf[4];
#pragma unroll
                    for (int kk = 0; kk < 4; ++kk) {
                        const int c16 = (kk * 4 + lg) ^ rx;
                        kf[kk] = *(const sx8*)(&sK[cur][row * DD + c16 * 8]);
                    }
#pragma unroll
                    for (int kk = 0; kk < 4; ++kk) {
                        st[0][j] = mfma16(kf[kk], qf[0][kk], st[0][j]);
                        st[1][j] = mfma16(kf[kk], qf[1][kk], st[1][j]);
                    }
                }
                // ---- issue first-half V loads early (latency hides under softmax) ----
                sx8 vf0[8];
#pragma unroll
                for (int n = 0; n < 8; ++n)
                    vf0[n] = *(const sx8*)(Vh + (size_t)(n * 16 + lr) * TT + k0 + lg * 8);

                // ---- softmax: q-row lane-local; in-reg tree + 2 shfl_xor ----
                const bool need_mask = (k0 + 63 > q0w);
                const int klocal = lg * 4;          // this lane's k-subcolumn base
#pragma unroll
                for (int i = 0; i < 2; ++i) {
                    if (need_mask) {
                        const int cl = q0w + i * 16 + lr - k0;   // max allowed k-local
#pragma unroll
                        for (int j = 0; j < 4; ++j)
#pragma unroll
                            for (int rg = 0; rg < 4; ++rg)
                                if (j * 16 + klocal + rg > cl) st[i][j][rg] = -1e30f;
                    }
                    f32x4 m4;
#pragma unroll
                    for (int rg = 0; rg < 4; ++rg)
                        m4[rg] = fmaxf(fmaxf(st[i][0][rg], st[i][1][rg]),
                                       fmaxf(st[i][2][rg], st[i][3][rg]));
                    float pm = fmaxf(fmaxf(m4[0], m4[1]), fmaxf(m4[2], m4[3]));
                    pm = fmaxf(pm, __shfl_xor(pm, 16));
                    pm = fmaxf(pm, __shfl_xor(pm, 32));
                    const float mold = mrow[i];
                    const bool resc = pm > mold + 8.0f;     // defer-max (T13)
                    const float mnew = resc ? pm : mold;
                    mrow[i] = mnew;
                    float rs = 0.0f;
#pragma unroll
                    for (int j = 0; j < 4; ++j) {
                        float p0 = __expf(st[i][j][0] - mnew);
                        float p1 = __expf(st[i][j][1] - mnew);
                        float p2 = __expf(st[i][j][2] - mnew);
                        float p3 = __expf(st[i][j][3] - mnew);
                        rs += (p0 + p1) + (p2 + p3);
                        *(uint2*)(myP + (i * 16 + lr) * PST + j * 16 + klocal) =
                            make_uint2(pkbf(p0, p1), pkbf(p2, p3));
                    }
                    rs += __shfl_xor(rs, 16);
                    rs += __shfl_xor(rs, 32);
                    const float sf = resc ? __expf(mold - mnew) : 1.0f;
                    lrow[i] = lrow[i] * sf + rs;
                    if (__any(resc)) {                       // rare with defer-max
                        f32x4 sfo;
#pragma unroll
                        for (int rg = 0; rg < 4; ++rg)
                            sfo[rg] = __shfl(sf, 4 * lg + rg);
#pragma unroll
                        for (int n = 0; n < 8; ++n) o[i][n] *= sfo;
                    }
                }
                // ensure P writes landed before cross-lane reads (per-wave region)
                asm volatile("s_waitcnt lgkmcnt(0)" ::: "memory");
                __builtin_amdgcn_sched_barrier(0);

                // ---- PV: P as A-operand, V^T as B-operand ----
                sx8 pa0[2], pa1[2];
                pa0[0] = *(const sx8*)(myP + (size_t)lr * PST + lg * 8);
                pa0[1] = *(const sx8*)(myP + (size_t)(16 + lr) * PST + lg * 8);
                pa1[0] = *(const sx8*)(myP + (size_t)lr * PST + 32 + lg * 8);
                pa1[1] = *(const sx8*)(myP + (size_t)(16 + lr) * PST + 32 + lg * 8);
#pragma unroll
                for (int n = 0; n < 8; ++n) {
                    o[0][n] = mfma16(pa0[0], vf0[n], o[0][n]);
                    o[1][n] = mfma16(pa0[1], vf0[n], o[1][n]);
                }
#pragma unroll
                for (int n = 0; n < 8; ++n) {
                    sx8 vf1 = *(const sx8*)(Vh + (size_t)(n * 16 + lr) * TT + k0 + 32 + lg * 8);
                    o[0][n] = mfma16(pa1[0], vf1, o[0][n]);
                    o[1][n] = mfma16(pa1[1], vf1, o[1][n]);
                }
            }
            __syncthreads();    // drains vmcnt (prefetch done) + all waves done with sK[cur]
            cur ^= 1;
        }

        // ---- epilogue: fetch l for this lane's O-rows, write strip ----
#pragma unroll
        for (int i = 0; i < 2; ++i) {
            f32x4 linv;
#pragma unroll
            for (int rg = 0; rg < 4; ++rg)
                linv[rg] = __shfl(lrow[i], 4 * lg + rg);
#pragma unroll
            for (int rg = 0; rg < 4; ++rg) {
                const float inv = 1.0f / linv[rg];
                const int tq = q0w + i * 16 + lg * 4 + rg;
                u16* orow = AO + ((size_t)(b * TT) + tq) * CC + h * DD + lr;
#pragma unroll
                for (int n = 0; n < 8; ++n)
                    orow[n * 16] = f2bf(o[i][n][rg] * inv);
            }
        }
    }
}

extern "C" void kernel_launch(void* const* d_in, const int* in_sizes, int n_in,
                              void* d_out, int out_size, void* d_ws, size_t ws_size,
                              hipStream_t stream) {
    const float* x     = (const float*)d_in[0];
    const float* freqs = (const float*)d_in[1];
    // d_in[2] = mask: causal, implemented analytically
    const float* w_qkv = (const float*)d_in[3];
    const float* w_out = (const float*)d_in[4];
    float* out = (float*)d_out;

    u16* ws   = (u16*)d_ws;
    u16* xb   = ws;
    u16* wqb  = xb   + (size_t)MM * CC;
    u16* wob  = wqb  + (size_t)FF * CC;
    u16* AO   = wob  + (size_t)CC * CC;      // attn output (b,t,h*d)
    u16* Qr   = AO   + (size_t)MM * CC;
    u16* Kr   = Qr   + (size_t)MM * CC;
    u16* Vt   = Kr   + (size_t)MM * CC;

    const int ncv = (MM * CC + FF * CC + CC * CC) / 8;
    k_cvt3<<<(ncv + 255) / 256, 256, 0, stream>>>(x, w_qkv, w_out, xb);

    // gemm0 with fused RoPE/split/V^T epilogue
    k_gemm<2><<<dim3(FF / 128, MM / 128), 256, 0, stream>>>(
        xb, wqb, nullptr, freqs, Qr, Kr, Vt, MM, FF, CC);
    k_attn<<<dim3(8, HH, BB), 256, 0, stream>>>(Qr, Kr, Vt, AO);
    k_gemm<1><<<dim3(CC / 128, MM / 128), 256, 0, stream>>>(
        AO, wob, out, nullptr, nullptr, nullptr, nullptr, MM, CC, CC);
}

// Round 15
// 516.139 us; speedup vs baseline: 1.0694x; 1.0694x over previous
//
#include <hip/hip_runtime.h>

typedef unsigned short u16;
typedef unsigned int   u32;

using sx8   = __attribute__((ext_vector_type(8))) short;   // 8 x bf16 bits
using f32x4 = __attribute__((ext_vector_type(4))) float;
using u16x8 = __attribute__((ext_vector_type(8))) unsigned short;

#define BB 4
#define TT 2048
#define CC 2048
#define HH 16
#define DD 128
#define FF 6144
#define MM 8192

static __device__ __forceinline__ u16 f2bf(float f) {
    u32 u = __builtin_bit_cast(u32, f);
    u32 lsb = (u >> 16) & 1u;
    u += 0x7fffu + lsb;
    return (u16)(u >> 16);
}
static __device__ __forceinline__ float bf2f(u16 b) {
    return __builtin_bit_cast(float, (u32)b << 16);
}
static __device__ __forceinline__ f32x4 mfma16(sx8 a, sx8 b, f32x4 c) {
    return __builtin_amdgcn_mfma_f32_16x16x32_bf16(a, b, c, 0, 0, 0);
}
static __device__ __forceinline__ u32 pkbf(float a, float b) {
    return (u32)f2bf(a) | ((u32)f2bf(b) << 16);
}

// ---------------- fused f32 -> bf16 convert for x, w_qkv, w_out ----------------
// destinations are contiguous in workspace: [xb | wqb | wob]
__global__ __launch_bounds__(256) void k_cvt3(const float* __restrict__ x,
                                              const float* __restrict__ wq,
                                              const float* __restrict__ wo,
                                              u16* __restrict__ dst) {
    const size_t n0 = (size_t)MM * CC / 8, n1 = n0 + (size_t)FF * CC / 8;
    const size_t n2 = n1 + (size_t)CC * CC / 8;
    size_t i = (size_t)blockIdx.x * 256 + threadIdx.x;
    if (i >= n2) return;
    const float* s;
    size_t off;
    if (i < n0)      { s = x;  off = i; }
    else if (i < n1) { s = wq; off = i - n0; }
    else             { s = wo; off = i - n1; }
    const float4* sp = (const float4*)s;
    float4 a = sp[2 * off], b = sp[2 * off + 1];
    u16x8 r;
    r[0] = f2bf(a.x); r[1] = f2bf(a.y); r[2] = f2bf(a.z); r[3] = f2bf(a.w);
    r[4] = f2bf(b.x); r[5] = f2bf(b.y); r[6] = f2bf(b.z); r[7] = f2bf(b.w);
    *(u16x8*)(dst + 8 * i) = r;
}

// ---------------- bf16 A(MxK) @ Bt(NxK)^T GEMM, m97 structure ----------------
// MODE 1: plain f32 C output (out-proj).
// MODE 2: fused epilogue — RoPE(Q,K) + QKV split + V transpose:
//   each 128-col tile = one head, one of Q/K/V (block-uniform).
//   RoPE pair partner via shfl_xor(1); Q pre-scaled by 1/sqrt(D);
//   V transposed through per-wave LDS (padded), coalesced 16B stores.
template <int MODE>
__global__ __launch_bounds__(256, 2) void k_gemm(const u16* __restrict__ A,
                                                 const u16* __restrict__ Bt,
                                                 float* __restrict__ Cf,
                                                 const float* __restrict__ freqs,
                                                 u16* __restrict__ Qo,
                                                 u16* __restrict__ Ko,
                                                 u16* __restrict__ Vt,
                                                 int M, int N, int K) {
    __shared__ __align__(16) u16 sA[128 * 32];
    __shared__ __align__(16) u16 sB[128 * 32];
    __shared__ __align__(16) u16 vT[4][64][17];     // MODE 2 V-transpose staging
    const int n0 = blockIdx.x * 128, m0 = blockIdx.y * 128;
    const int tid = threadIdx.x, w = tid >> 6, l = tid & 63;
    const int wm = w >> 1, wn = w & 1;
    const int lr = l & 15, lg = l >> 4;
    f32x4 acc[4][4] = {};

    const int idx0 = w * 128 + l;
    const int idx1 = idx0 + 64;
    const int ra0 = idx0 >> 2, ca0 = (idx0 & 3) * 8;
    const int ra1 = idx1 >> 2, ca1 = (idx1 & 3) * 8;
    const u16* Ar0 = A + (size_t)(m0 + ra0) * K + ca0;
    const u16* Ar1 = A + (size_t)(m0 + ra1) * K + ca1;
    const u16* Br0 = Bt + (size_t)(n0 + ra0) * K + ca0;
    const u16* Br1 = Bt + (size_t)(n0 + ra1) * K + ca1;
    u16* sAd0 = sA + (w * 2 + 0) * 512;
    u16* sAd1 = sA + (w * 2 + 1) * 512;
    u16* sBd0 = sB + (w * 2 + 0) * 512;
    u16* sBd1 = sB + (w * 2 + 1) * 512;

    for (int k0 = 0; k0 < K; k0 += 32) {
        __builtin_amdgcn_global_load_lds(
            (const __attribute__((address_space(1))) void*)(Ar0 + k0),
            (__attribute__((address_space(3))) void*)sAd0, 16, 0, 0);
        __builtin_amdgcn_global_load_lds(
            (const __attribute__((address_space(1))) void*)(Ar1 + k0),
            (__attribute__((address_space(3))) void*)sAd1, 16, 0, 0);
        __builtin_amdgcn_global_load_lds(
            (const __attribute__((address_space(1))) void*)(Br0 + k0),
            (__attribute__((address_space(3))) void*)sBd0, 16, 0, 0);
        __builtin_amdgcn_global_load_lds(
            (const __attribute__((address_space(1))) void*)(Br1 + k0),
            (__attribute__((address_space(3))) void*)sBd1, 16, 0, 0);
        __syncthreads();
        sx8 af[4], bfr[4];
#pragma unroll
        for (int i = 0; i < 4; i++)
            af[i] = *(const sx8*)(sA + (wm * 64 + i * 16 + lr) * 32 + lg * 8);
#pragma unroll
        for (int j = 0; j < 4; j++)
            bfr[j] = *(const sx8*)(sB + (wn * 64 + j * 16 + lr) * 32 + lg * 8);
#pragma unroll
        for (int i = 0; i < 4; i++)
#pragma unroll
            for (int j = 0; j < 4; j++)
                acc[i][j] = mfma16(af[i], bfr[j], acc[i][j]);
        __syncthreads();
    }

    if (MODE == 1) {
        // plain f32 epilogue: D row = (lane>>4)*4+reg, col = lane&15
#pragma unroll
        for (int i = 0; i < 4; i++) {
            const int mr = m0 + wm * 64 + i * 16 + lg * 4;
#pragma unroll
            for (int j = 0; j < 4; j++) {
                const int nc = n0 + wn * 64 + j * 16 + lr;
#pragma unroll
                for (int rg = 0; rg < 4; rg++)
                    Cf[(size_t)(mr + rg) * N + nc] = acc[i][j][rg];
            }
        }
    } else {
        // fused qkv epilogue
        const int b = m0 >> 11;                 // batch (block-uniform)
        const int t0blk = m0 & 2047;
        const int kind = n0 >> 11;              // 0=Q 1=K 2=V (block-uniform)
        const int h = (n0 & 2047) >> 7;         // head (block-uniform)
        const size_t bh = (size_t)(b * HH + h);
        if (kind < 2) {
            u16* dst = (kind == 0 ? Qo : Ko) + bh * (size_t)(TT * DD);
            const float qs = (kind == 0) ? 0.08838834764831845f : 1.0f;
#pragma unroll
            for (int i = 0; i < 4; i++) {
#pragma unroll
                for (int j = 0; j < 4; j++) {
                    const int d = wn * 64 + j * 16 + lr;       // 0..127
                    const int dp2 = (d >> 1) * 2;
#pragma unroll
                    for (int rg = 0; rg < 4; rg++) {
                        const int t = t0blk + wm * 64 + i * 16 + lg * 4 + rg;
                        float v = acc[i][j][rg];
                        float p = __shfl_xor(v, 1);
                        float2 cs = *(const float2*)(freqs + (size_t)t * DD + dp2);
                        float r = (lr & 1) ? (p * cs.y + v * cs.x)
                                           : (v * cs.x - p * cs.y);
                        dst[(size_t)t * DD + d] = f2bf(r * qs);
                    }
                }
            }
        } else {
            u16* dstV = Vt + bh * (size_t)(DD * TT);
            const int t0w = t0blk + wm * 64;
            const int dl = l >> 2, seg = l & 3;
#pragma unroll
            for (int j = 0; j < 4; ++j) {
#pragma unroll
                for (int i = 0; i < 4; ++i)
#pragma unroll
                    for (int rg = 0; rg < 4; ++rg)
                        vT[w][i * 16 + lg * 4 + rg][lr] = f2bf(acc[i][j][rg]);
                asm volatile("s_waitcnt lgkmcnt(0)" ::: "memory");
                __builtin_amdgcn_sched_barrier(0);
                u16x8 t2[2];
#pragma unroll
                for (int jj = 0; jj < 16; ++jj)
                    t2[jj >> 3][jj & 7] = vT[w][seg * 16 + jj][dl];
                const int dg = wn * 64 + j * 16 + dl;
                u16* orow = dstV + (size_t)dg * TT + t0w + seg * 16;
                *(u16x8*)orow = t2[0];
                *((u16x8*)orow + 1) = t2[1];
                asm volatile("s_waitcnt lgkmcnt(0)" ::: "memory");   // reads done before next j overwrites
                __builtin_amdgcn_sched_barrier(0);
            }
        }
    }
}

// ---------------- causal flash attention: 4 waves x 32 q-rows, KVBLK=64 ----------------
// Round-5 schedule (512 uniform blocks, strip-pair (x,15-x), 2-phase dbuf K staging)
// + swapped QK^T: S^T = mfma(K,Q) puts each q-row's scores lane-local
//   (row = lane&15, 16 k-vals in regs) -> in-reg reduce + 2 shfl_xor, packed b64 P writes.
#define KV 64
#define PST 68

__global__ __launch_bounds__(256, 2) void k_attn(const u16* __restrict__ Q,
                                                 const u16* __restrict__ K,
                                                 const u16* __restrict__ Vt,
                                                 u16* __restrict__ AO) {
    const int fid = blockIdx.x + 8 * blockIdx.y + 128 * blockIdx.z;
    const int xg = fid >> 6;                // 0..7  (strip-pair index)
    const int hb = fid & 63;
    const int h = hb & 15, b = hb >> 4;

    const int tid = threadIdx.x, w = tid >> 6, l = tid & 63;
    const int lr = l & 15, lg = l >> 4;
    const size_t bh = (size_t)(b * HH + h);
    const u16* Qh = Q + bh * TT * DD;
    const u16* Kh = K + bh * TT * DD;
    const u16* Vh = Vt + bh * DD * TT;

    __shared__ __align__(16) u16 sK[2][KV * DD];    // 32 KB, double-buffered, XOR-swizzled
    __shared__ __align__(16) u16 sP[4][32 * PST];   // 17 KB, per-wave P tiles
    u16* myP = sP[w];

    const int strow = tid >> 4;       // staging sub-row 0..15
    const int sc16  = tid & 15;       // staging 16B-column

    for (int rep = 0; rep < 2; ++rep) {
        const int g = rep ? (15 - xg) : xg;     // strip-group (128 rows)
        const int q0w = g * 128 + w * 32;       // this wave's first q row
        const int nt = 2 * g + 2;               // k-tiles of 64

        sx8 qf[2][4];
#pragma unroll
        for (int i = 0; i < 2; i++)
#pragma unroll
            for (int kk = 0; kk < 4; kk++)
                qf[i][kk] = *(const sx8*)(Qh + (size_t)(q0w + i * 16 + lr) * DD + kk * 32 + lg * 8);

        f32x4 o[2][8] = {};
        float mrow[2] = {-1e30f, -1e30f};
        float lrow[2] = {0.0f, 0.0f};

        // prologue: stage tile 0 into buf 0 (linear dest, inverse-swizzled source)
#pragma unroll
        for (int i = 0; i < 4; ++i) {
            const int row = i * 16 + strow;
            const int scol = (sc16 ^ (row & 7)) * 8;
            __builtin_amdgcn_global_load_lds(
                (const __attribute__((address_space(1))) void*)(Kh + (size_t)row * DD + scol),
                (__attribute__((address_space(3))) void*)(&sK[0][i * 2048 + w * 512]),
                16, 0, 0);
        }
        __syncthreads();

        int cur = 0;
        for (int t = 0; t < nt; ++t) {
            const int k0 = t * KV;
            if (t + 1 < nt) {               // prefetch next K tile into buf^1
                const int kn = k0 + KV;
#pragma unroll
                for (int i = 0; i < 4; ++i) {
                    const int row = i * 16 + strow;
                    const int scol = (sc16 ^ (row & 7)) * 8;
                    __builtin_amdgcn_global_load_lds(
                        (const __attribute__((address_space(1))) void*)(Kh + (size_t)(kn + row) * DD + scol),
                        (__attribute__((address_space(3))) void*)(&sK[cur ^ 1][i * 2048 + w * 512]),
                        16, 0, 0);
                }
            }
            if (k0 <= q0w) {                // causally active for this wave
                // ---- S^T = K·Q^T from swizzled LDS: k on (lg,rg), q-row on lr ----
                f32x4 st[2][4] = {};
#pragma unroll
                for (int j = 0; j < 4; ++j) {
                    const int row = j * 16 + lr;
                    const int rx = row & 7;
                    sx8 kf[4];
#pragma unroll
                    for (int kk = 0; kk < 4; ++kk) {
                        const int c16 = (kk * 4 + lg) ^ rx;
                        kf[kk] = *(const sx8*)(&sK[cur][row * DD + c16 * 8]);
                    }
#pragma unroll
                    for (int kk = 0; kk < 4; ++kk) {
                        st[0][j] = mfma16(kf[kk], qf[0][kk], st[0][j]);
                        st[1][j] = mfma16(kf[kk], qf[1][kk], st[1][j]);
                    }
                }
                // ---- issue first-half V loads early (latency hides under softmax) ----
                sx8 vf0[8];
#pragma unroll
                for (int n = 0; n < 8; ++n)
                    vf0[n] = *(const sx8*)(Vh + (size_t)(n * 16 + lr) * TT + k0 + lg * 8);

                // ---- softmax: q-row lane-local; in-reg tree + 2 shfl_xor ----
                const bool need_mask = (k0 + 63 > q0w);
                const int klocal = lg * 4;          // this lane's k-subcolumn base
#pragma unroll
                for (int i = 0; i < 2; ++i) {
                    if (need_mask) {
                        const int cl = q0w + i * 16 + lr - k0;   // max allowed k-local
#pragma unroll
                        for (int j = 0; j < 4; ++j)
#pragma unroll
                            for (int rg = 0; rg < 4; ++rg)
                                if (j * 16 + klocal + rg > cl) st[i][j][rg] = -1e30f;
                    }
                    f32x4 m4;
#pragma unroll
                    for (int rg = 0; rg < 4; ++rg)
                        m4[rg] = fmaxf(fmaxf(st[i][0][rg], st[i][1][rg]),
                                       fmaxf(st[i][2][rg], st[i][3][rg]));
                    float pm = fmaxf(fmaxf(m4[0], m4[1]), fmaxf(m4[2], m4[3]));
                    pm = fmaxf(pm, __shfl_xor(pm, 16));
                    pm = fmaxf(pm, __shfl_xor(pm, 32));
                    const float mold = mrow[i];
                    const bool resc = pm > mold + 8.0f;     // defer-max (T13)
                    const float mnew = resc ? pm : mold;
                    mrow[i] = mnew;
                    float rs = 0.0f;
#pragma unroll
                    for (int j = 0; j < 4; ++j) {
                        float p0 = __expf(st[i][j][0] - mnew);
                        float p1 = __expf(st[i][j][1] - mnew);
                        float p2 = __expf(st[i][j][2] - mnew);
                        float p3 = __expf(st[i][j][3] - mnew);
                        rs += (p0 + p1) + (p2 + p3);
                        *(uint2*)(myP + (i * 16 + lr) * PST + j * 16 + klocal) =
                            make_uint2(pkbf(p0, p1), pkbf(p2, p3));
                    }
                    rs += __shfl_xor(rs, 16);
                    rs += __shfl_xor(rs, 32);
                    const float sf = resc ? __expf(mold - mnew) : 1.0f;
                    lrow[i] = lrow[i] * sf + rs;
                    if (__any(resc)) {                       // rare with defer-max
                        f32x4 sfo;
#pragma unroll
                        for (int rg = 0; rg < 4; ++rg)
                            sfo[rg] = __shfl(sf, 4 * lg + rg);
#pragma unroll
                        for (int n = 0; n < 8; ++n) o[i][n] *= sfo;
                    }
                }
                // ensure P writes landed before cross-lane reads (per-wave region)
                asm volatile("s_waitcnt lgkmcnt(0)" ::: "memory");
                __builtin_amdgcn_sched_barrier(0);

                // ---- PV: P as A-operand, V^T as B-operand ----
                sx8 pa0[2], pa1[2];
                pa0[0] = *(const sx8*)(myP + (size_t)lr * PST + lg * 8);
                pa0[1] = *(const sx8*)(myP + (size_t)(16 + lr) * PST + lg * 8);
                pa1[0] = *(const sx8*)(myP + (size_t)lr * PST + 32 + lg * 8);
                pa1[1] = *(const sx8*)(myP + (size_t)(16 + lr) * PST + 32 + lg * 8);
#pragma unroll
                for (int n = 0; n < 8; ++n) {
                    o[0][n] = mfma16(pa0[0], vf0[n], o[0][n]);
                    o[1][n] = mfma16(pa0[1], vf0[n], o[1][n]);
                }
#pragma unroll
                for (int n = 0; n < 8; ++n) {
                    sx8 vf1 = *(const sx8*)(Vh + (size_t)(n * 16 + lr) * TT + k0 + 32 + lg * 8);
                    o[0][n] = mfma16(pa1[0], vf1, o[0][n]);
                    o[1][n] = mfma16(pa1[1], vf1, o[1][n]);
                }
            }
            __syncthreads();    // drains vmcnt (prefetch done) + all waves done with sK[cur]
            cur ^= 1;
        }

        // ---- epilogue: fetch l for this lane's O-rows, write strip ----
#pragma unroll
        for (int i = 0; i < 2; ++i) {
            f32x4 linv;
#pragma unroll
            for (int rg = 0; rg < 4; ++rg)
                linv[rg] = __shfl(lrow[i], 4 * lg + rg);
#pragma unroll
            for (int rg = 0; rg < 4; ++rg) {
                const float inv = 1.0f / linv[rg];
                const int tq = q0w + i * 16 + lg * 4 + rg;
                u16* orow = AO + ((size_t)(b * TT) + tq) * CC + h * DD + lr;
#pragma unroll
                for (int n = 0; n < 8; ++n)
                    orow[n * 16] = f2bf(o[i][n][rg] * inv);
            }
        }
    }
}

extern "C" void kernel_launch(void* const* d_in, const int* in_sizes, int n_in,
                              void* d_out, int out_size, void* d_ws, size_t ws_size,
                              hipStream_t stream) {
    const float* x     = (const float*)d_in[0];
    const float* freqs = (const float*)d_in[1];
    // d_in[2] = mask: causal, implemented analytically
    const float* w_qkv = (const float*)d_in[3];
    const float* w_out = (const float*)d_in[4];
    float* out = (float*)d_out;

    u16* ws   = (u16*)d_ws;
    u16* xb   = ws;
    u16* wqb  = xb   + (size_t)MM * CC;
    u16* wob  = wqb  + (size_t)FF * CC;
    u16* AO   = wob  + (size_t)CC * CC;      // attn output (b,t,h*d)
    u16* Qr   = AO   + (size_t)MM * CC;
    u16* Kr   = Qr   + (size_t)MM * CC;
    u16* Vt   = Kr   + (size_t)MM * CC;

    const int ncv = (MM * CC + FF * CC + CC * CC) / 8;
    k_cvt3<<<(ncv + 255) / 256, 256, 0, stream>>>(x, w_qkv, w_out, xb);

    // gemm0 with fused RoPE/split/V^T epilogue (k_rope eliminated)
    k_gemm<2><<<dim3(FF / 128, MM / 128), 256, 0, stream>>>(
        xb, wqb, nullptr, freqs, Qr, Kr, Vt, MM, FF, CC);
    k_attn<<<dim3(8, HH, BB), 256, 0, stream>>>(Qr, Kr, Vt, AO);
    k_gemm<1><<<dim3(CC / 128, MM / 128), 256, 0, stream>>>(
        AO, wob, out, nullptr, nullptr, nullptr, nullptr, MM, CC, CC);
}

// Round 16
// 486.992 us; speedup vs baseline: 1.1334x; 1.0599x over previous
//
#include <hip/hip_runtime.h>

typedef unsigned short u16;
typedef unsigned int   u32;

using sx8   = __attribute__((ext_vector_type(8))) short;   // 8 x bf16 bits
using f32x4 = __attribute__((ext_vector_type(4))) float;
using u16x8 = __attribute__((ext_vector_type(8))) unsigned short;

#define BB 4
#define TT 2048
#define CC 2048
#define HH 16
#define DD 128
#define FF 6144
#define MM 8192

static __device__ __forceinline__ u16 f2bf(float f) {
    u32 u = __builtin_bit_cast(u32, f);
    u32 lsb = (u >> 16) & 1u;
    u += 0x7fffu + lsb;
    return (u16)(u >> 16);
}
static __device__ __forceinline__ float bf2f(u16 b) {
    return __builtin_bit_cast(float, (u32)b << 16);
}
static __device__ __forceinline__ f32x4 mfma16(sx8 a, sx8 b, f32x4 c) {
    return __builtin_amdgcn_mfma_f32_16x16x32_bf16(a, b, c, 0, 0, 0);
}
static __device__ __forceinline__ u32 pkbf(float a, float b) {
    return (u32)f2bf(a) | ((u32)f2bf(b) << 16);
}

// ---------------- fused f32 -> bf16 convert for x, w_qkv, w_out ----------------
__global__ __launch_bounds__(256) void k_cvt3(const float* __restrict__ x,
                                              const float* __restrict__ wq,
                                              const float* __restrict__ wo,
                                              u16* __restrict__ dst) {
    const size_t n0 = (size_t)MM * CC / 8, n1 = n0 + (size_t)FF * CC / 8;
    const size_t n2 = n1 + (size_t)CC * CC / 8;
    size_t i = (size_t)blockIdx.x * 256 + threadIdx.x;
    if (i >= n2) return;
    const float* s;
    size_t off;
    if (i < n0)      { s = x;  off = i; }
    else if (i < n1) { s = wq; off = i - n0; }
    else             { s = wo; off = i - n1; }
    const float4* sp = (const float4*)s;
    float4 a = sp[2 * off], b = sp[2 * off + 1];
    u16x8 r;
    r[0] = f2bf(a.x); r[1] = f2bf(a.y); r[2] = f2bf(a.z); r[3] = f2bf(a.w);
    r[4] = f2bf(b.x); r[5] = f2bf(b.y); r[6] = f2bf(b.z); r[7] = f2bf(b.w);
    *(u16x8*)(dst + 8 * i) = r;
}

// ---------------- bf16 A(MxK) @ Bt(NxK)^T GEMM, m97 structure, BK=64 ----------------
// 128x128 tile, BK=64 (32 iters: half the barrier/drain count of BK=32),
// both-sides granule XOR swizzle (g ^= row&7): 2-way max on ds_read_b128, and
// global_load_lds source pre-swizzled so linear LDS dest stays correct.
// MODE 1: plain f32 C output (out-proj).
// MODE 2: fused epilogue — RoPE(Q,K) + QKV split + V transpose.
template <int MODE>
__global__ __launch_bounds__(256, 2) void k_gemm(const u16* __restrict__ A,
                                                 const u16* __restrict__ Bt,
                                                 float* __restrict__ Cf,
                                                 const float* __restrict__ freqs,
                                                 u16* __restrict__ Qo,
                                                 u16* __restrict__ Ko,
                                                 u16* __restrict__ Vt,
                                                 int M, int N, int K) {
    __shared__ __align__(16) u16 sA[128 * 64];      // 16 KB
    __shared__ __align__(16) u16 sB[128 * 64];      // 16 KB
    __shared__ __align__(16) u16 vT[4][64][17];     // MODE 2 V-transpose staging
    const int n0 = blockIdx.x * 128, m0 = blockIdx.y * 128;
    const int tid = threadIdx.x, w = tid >> 6, l = tid & 63;
    const int wm = w >> 1, wn = w & 1;
    const int lr = l & 15, lg = l >> 4;
    f32x4 acc[4][4] = {};

    // staging: 4 GLL-calls each for A,B per K-iter; call c covers rows c*32 + (tid>>3)
    const int srow = tid >> 3;                      // 0..31 (row within 32-row chunk)
    const int sgr  = (tid & 7) ^ (srow & 7);        // pre-swizzled source granule
    const u16* As = A  + (size_t)(m0 + srow) * K + sgr * 8;
    const u16* Bs = Bt + (size_t)(n0 + srow) * K + sgr * 8;
    const size_t r32 = (size_t)32 * K;              // 32-row source step
    u16* dA = sA + w * 512;                         // + c*2048 (u16)
    u16* dB = sB + w * 512;

    // read-side: row*64 + ((ks*4+lg)^(row&7))*8 ; row&7 == lr&7
    const int rx = lr & 7;
    const int g0 = ((0 + lg) ^ rx) * 8;             // ks=0 granule offset
    const int g1 = ((4 + lg) ^ rx) * 8;             // ks=1 granule offset

    for (int k0 = 0; k0 < K; k0 += 64) {
#pragma unroll
        for (int c = 0; c < 4; ++c) {
            __builtin_amdgcn_global_load_lds(
                (const __attribute__((address_space(1))) void*)(As + (size_t)c * r32 + k0),
                (__attribute__((address_space(3))) void*)(dA + c * 2048), 16, 0, 0);
            __builtin_amdgcn_global_load_lds(
                (const __attribute__((address_space(1))) void*)(Bs + (size_t)c * r32 + k0),
                (__attribute__((address_space(3))) void*)(dB + c * 2048), 16, 0, 0);
        }
        __syncthreads();
        sx8 af[4][2], bfr[4][2];
#pragma unroll
        for (int i = 0; i < 4; i++) {
            const int ra = (wm * 64 + i * 16 + lr) * 64;
            af[i][0] = *(const sx8*)(sA + ra + g0);
            af[i][1] = *(const sx8*)(sA + ra + g1);
        }
#pragma unroll
        for (int j = 0; j < 4; j++) {
            const int rb = (wn * 64 + j * 16 + lr) * 64;
            bfr[j][0] = *(const sx8*)(sB + rb + g0);
            bfr[j][1] = *(const sx8*)(sB + rb + g1);
        }
#pragma unroll
        for (int ks = 0; ks < 2; ++ks)
#pragma unroll
            for (int i = 0; i < 4; i++)
#pragma unroll
                for (int j = 0; j < 4; j++)
                    acc[i][j] = mfma16(af[i][ks], bfr[j][ks], acc[i][j]);
        __syncthreads();
    }

    if (MODE == 1) {
        // plain f32 epilogue: D row = (lane>>4)*4+reg, col = lane&15
#pragma unroll
        for (int i = 0; i < 4; i++) {
            const int mr = m0 + wm * 64 + i * 16 + lg * 4;
#pragma unroll
            for (int j = 0; j < 4; j++) {
                const int nc = n0 + wn * 64 + j * 16 + lr;
#pragma unroll
                for (int rg = 0; rg < 4; rg++)
                    Cf[(size_t)(mr + rg) * N + nc] = acc[i][j][rg];
            }
        }
    } else {
        // fused qkv epilogue
        const int b = m0 >> 11;                 // batch (block-uniform)
        const int t0blk = m0 & 2047;
        const int kind = n0 >> 11;              // 0=Q 1=K 2=V (block-uniform)
        const int h = (n0 & 2047) >> 7;         // head (block-uniform)
        const size_t bh = (size_t)(b * HH + h);
        if (kind < 2) {
            u16* dst = (kind == 0 ? Qo : Ko) + bh * (size_t)(TT * DD);
            const float qs = (kind == 0) ? 0.08838834764831845f : 1.0f;
#pragma unroll
            for (int i = 0; i < 4; i++) {
#pragma unroll
                for (int j = 0; j < 4; j++) {
                    const int d = wn * 64 + j * 16 + lr;       // 0..127
                    const int dp2 = (d >> 1) * 2;
#pragma unroll
                    for (int rg = 0; rg < 4; rg++) {
                        const int t = t0blk + wm * 64 + i * 16 + lg * 4 + rg;
                        float v = acc[i][j][rg];
                        float p = __shfl_xor(v, 1);
                        float2 cs = *(const float2*)(freqs + (size_t)t * DD + dp2);
                        float r = (lr & 1) ? (p * cs.y + v * cs.x)
                                           : (v * cs.x - p * cs.y);
                        dst[(size_t)t * DD + d] = f2bf(r * qs);
                    }
                }
            }
        } else {
            u16* dstV = Vt + bh * (size_t)(DD * TT);
            const int t0w = t0blk + wm * 64;
            const int dl = l >> 2, seg = l & 3;
#pragma unroll
            for (int j = 0; j < 4; ++j) {
#pragma unroll
                for (int i = 0; i < 4; ++i)
#pragma unroll
                    for (int rg = 0; rg < 4; ++rg)
                        vT[w][i * 16 + lg * 4 + rg][lr] = f2bf(acc[i][j][rg]);
                asm volatile("s_waitcnt lgkmcnt(0)" ::: "memory");
                __builtin_amdgcn_sched_barrier(0);
                u16x8 t2[2];
#pragma unroll
                for (int jj = 0; jj < 16; ++jj)
                    t2[jj >> 3][jj & 7] = vT[w][seg * 16 + jj][dl];
                const int dg = wn * 64 + j * 16 + dl;
                u16* orow = dstV + (size_t)dg * TT + t0w + seg * 16;
                *(u16x8*)orow = t2[0];
                *((u16x8*)orow + 1) = t2[1];
                asm volatile("s_waitcnt lgkmcnt(0)" ::: "memory");   // reads done before next j overwrites
                __builtin_amdgcn_sched_barrier(0);
            }
        }
    }
}

// ---------------- causal flash attention: 4 waves x 32 q-rows, KVBLK=64 ----------------
// Round-5 schedule (512 uniform blocks, strip-pair (x,15-x), 2-phase dbuf K staging)
// + swapped QK^T: S^T = mfma(K,Q) puts each q-row's scores lane-local
//   (row = lane&15, 16 k-vals in regs) -> in-reg reduce + 2 shfl_xor, packed b64 P writes.
#define KV 64
#define PST 68

__global__ __launch_bounds__(256, 2) void k_attn(const u16* __restrict__ Q,
                                                 const u16* __restrict__ K,
                                                 const u16* __restrict__ Vt,
                                                 u16* __restrict__ AO) {
    const int fid = blockIdx.x + 8 * blockIdx.y + 128 * blockIdx.z;
    const int xg = fid >> 6;                // 0..7  (strip-pair index)
    const int hb = fid & 63;
    const int h = hb & 15, b = hb >> 4;

    const int tid = threadIdx.x, w = tid >> 6, l = tid & 63;
    const int lr = l & 15, lg = l >> 4;
    const size_t bh = (size_t)(b * HH + h);
    const u16* Qh = Q + bh * TT * DD;
    const u16* Kh = K + bh * TT * DD;
    const u16* Vh = Vt + bh * DD * TT;

    __shared__ __align__(16) u16 sK[2][KV * DD];    // 32 KB, double-buffered, XOR-swizzled
    __shared__ __align__(16) u16 sP[4][32 * PST];   // 17 KB, per-wave P tiles
    u16* myP = sP[w];

    const int strow = tid >> 4;       // staging sub-row 0..15
    const int sc16  = tid & 15;       // staging 16B-column

    for (int rep = 0; rep < 2; ++rep) {
        const int g = rep ? (15 - xg) : xg;     // strip-group (128 rows)
        const int q0w = g * 128 + w * 32;       // this wave's first q row
        const int nt = 2 * g + 2;               // k-tiles of 64

        sx8 qf[2][4];
#pragma unroll
        for (int i = 0; i < 2; i++)
#pragma unroll
            for (int kk = 0; kk < 4; kk++)
                qf[i][kk] = *(const sx8*)(Qh + (size_t)(q0w + i * 16 + lr) * DD + kk * 32 + lg * 8);

        f32x4 o[2][8] = {};
        float mrow[2] = {-1e30f, -1e30f};
        float lrow[2] = {0.0f, 0.0f};

        // prologue: stage tile 0 into buf 0 (linear dest, inverse-swizzled source)
#pragma unroll
        for (int i = 0; i < 4; ++i) {
            const int row = i * 16 + strow;
            const int scol = (sc16 ^ (row & 7)) * 8;
            __builtin_amdgcn_global_load_lds(
                (const __attribute__((address_space(1))) void*)(Kh + (size_t)row * DD + scol),
                (__attribute__((address_space(3))) void*)(&sK[0][i * 2048 + w * 512]),
                16, 0, 0);
        }
        __syncthreads();

        int cur = 0;
        for (int t = 0; t < nt; ++t) {
            const int k0 = t * KV;
            if (t + 1 < nt) {               // prefetch next K tile into buf^1
                const int kn = k0 + KV;
#pragma unroll
                for (int i = 0; i < 4; ++i) {
                    const int row = i * 16 + strow;
                    const int scol = (sc16 ^ (row & 7)) * 8;
                    __builtin_amdgcn_global_load_lds(
                        (const __attribute__((address_space(1))) void*)(Kh + (size_t)(kn + row) * DD + scol),
                        (__attribute__((address_space(3))) void*)(&sK[cur ^ 1][i * 2048 + w * 512]),
                        16, 0, 0);
                }
            }
            if (k0 <= q0w) {                // causally active for this wave
                // ---- S^T = K·Q^T from swizzled LDS: k on (lg,rg), q-row on lr ----
                f32x4 st[2][4] = {};
#pragma unroll
                for (int j = 0; j < 4; ++j) {
                    const int row = j * 16 + lr;
                    const int rx = row & 7;
                    sx8 kf[4];
#pragma unroll
                    for (int kk = 0; kk < 4; ++kk) {
                        const int c16 = (kk * 4 + lg) ^ rx;
                        kf[kk] = *(const sx8*)(&sK[cur][row * DD + c16 * 8]);
                    }
#pragma unroll
                    for (int kk = 0; kk < 4; ++kk) {
                        st[0][j] = mfma16(kf[kk], qf[0][kk], st[0][j]);
                        st[1][j] = mfma16(kf[kk], qf[1][kk], st[1][j]);
                    }
                }
                // ---- issue first-half V loads early (latency hides under softmax) ----
                sx8 vf0[8];
#pragma unroll
                for (int n = 0; n < 8; ++n)
                    vf0[n] = *(const sx8*)(Vh + (size_t)(n * 16 + lr) * TT + k0 + lg * 8);

                // ---- softmax: q-row lane-local; in-reg tree + 2 shfl_xor ----
                const bool need_mask = (t == nt - 1) && (k0 + 63 > q0w);
                const int klocal = lg * 4;          // this lane's k-subcolumn base
#pragma unroll
                for (int i = 0; i < 2; ++i) {
                    if (need_mask || (k0 + 63 > q0w)) {
                        const int cl = q0w + i * 16 + lr - k0;   // max allowed k-local
#pragma unroll
                        for (int j = 0; j < 4; ++j)
#pragma unroll
                            for (int rg = 0; rg < 4; ++rg)
                                if (j * 16 + klocal + rg > cl) st[i][j][rg] = -1e30f;
                    }
                    f32x4 m4;
#pragma unroll
                    for (int rg = 0; rg < 4; ++rg)
                        m4[rg] = fmaxf(fmaxf(st[i][0][rg], st[i][1][rg]),
                                       fmaxf(st[i][2][rg], st[i][3][rg]));
                    float pm = fmaxf(fmaxf(m4[0], m4[1]), fmaxf(m4[2], m4[3]));
                    pm = fmaxf(pm, __shfl_xor(pm, 16));
                    pm = fmaxf(pm, __shfl_xor(pm, 32));
                    const float mold = mrow[i];
                    const bool resc = pm > mold + 8.0f;     // defer-max (T13)
                    const float mnew = resc ? pm : mold;
                    mrow[i] = mnew;
                    float rs = 0.0f;
#pragma unroll
                    for (int j = 0; j < 4; ++j) {
                        float p0 = __expf(st[i][j][0] - mnew);
                        float p1 = __expf(st[i][j][1] - mnew);
                        float p2 = __expf(st[i][j][2] - mnew);
                        float p3 = __expf(st[i][j][3] - mnew);
                        rs += (p0 + p1) + (p2 + p3);
                        *(uint2*)(myP + (i * 16 + lr) * PST + j * 16 + klocal) =
                            make_uint2(pkbf(p0, p1), pkbf(p2, p3));
                    }
                    rs += __shfl_xor(rs, 16);
                    rs += __shfl_xor(rs, 32);
                    const float sf = resc ? __expf(mold - mnew) : 1.0f;
                    lrow[i] = lrow[i] * sf + rs;
                    if (__any(resc)) {                       // rare with defer-max
                        f32x4 sfo;
#pragma unroll
                        for (int rg = 0; rg < 4; ++rg)
                            sfo[rg] = __shfl(sf, 4 * lg + rg);
#pragma unroll
                        for (int n = 0; n < 8; ++n) o[i][n] *= sfo;
                    }
                }
                // ensure P writes landed before cross-lane reads (per-wave region)
                asm volatile("s_waitcnt lgkmcnt(0)" ::: "memory");
                __builtin_amdgcn_sched_barrier(0);

                // ---- PV: P as A-operand, V^T as B-operand ----
                sx8 pa0[2], pa1[2];
                pa0[0] = *(const sx8*)(myP + (size_t)lr * PST + lg * 8);
                pa0[1] = *(const sx8*)(myP + (size_t)(16 + lr) * PST + lg * 8);
                pa1[0] = *(const sx8*)(myP + (size_t)lr * PST + 32 + lg * 8);
                pa1[1] = *(const sx8*)(myP + (size_t)(16 + lr) * PST + 32 + lg * 8);
#pragma unroll
                for (int n = 0; n < 8; ++n) {
                    o[0][n] = mfma16(pa0[0], vf0[n], o[0][n]);
                    o[1][n] = mfma16(pa0[1], vf0[n], o[1][n]);
                }
#pragma unroll
                for (int n = 0; n < 8; ++n) {
                    sx8 vf1 = *(const sx8*)(Vh + (size_t)(n * 16 + lr) * TT + k0 + 32 + lg * 8);
                    o[0][n] = mfma16(pa1[0], vf1, o[0][n]);
                    o[1][n] = mfma16(pa1[1], vf1, o[1][n]);
                }
            }
            __syncthreads();    // drains vmcnt (prefetch done) + all waves done with sK[cur]
            cur ^= 1;
        }

        // ---- epilogue: fetch l for this lane's O-rows, write strip ----
#pragma unroll
        for (int i = 0; i < 2; ++i) {
            f32x4 linv;
#pragma unroll
            for (int rg = 0; rg < 4; ++rg)
                linv[rg] = __shfl(lrow[i], 4 * lg + rg);
#pragma unroll
            for (int rg = 0; rg < 4; ++rg) {
                const float inv = 1.0f / linv[rg];
                const int tq = q0w + i * 16 + lg * 4 + rg;
                u16* orow = AO + ((size_t)(b * TT) + tq) * CC + h * DD + lr;
#pragma unroll
                for (int n = 0; n < 8; ++n)
                    orow[n * 16] = f2bf(o[i][n][rg] * inv);
            }
        }
    }
}

extern "C" void kernel_launch(void* const* d_in, const int* in_sizes, int n_in,
                              void* d_out, int out_size, void* d_ws, size_t ws_size,
                              hipStream_t stream) {
    const float* x     = (const float*)d_in[0];
    const float* freqs = (const float*)d_in[1];
    // d_in[2] = mask: causal, implemented analytically
    const float* w_qkv = (const float*)d_in[3];
    const float* w_out = (const float*)d_in[4];
    float* out = (float*)d_out;

    u16* ws   = (u16*)d_ws;
    u16* xb   = ws;
    u16* wqb  = xb   + (size_t)MM * CC;
    u16* wob  = wqb  + (size_t)FF * CC;
    u16* AO   = wob  + (size_t)CC * CC;      // attn output (b,t,h*d)
    u16* Qr   = AO   + (size_t)MM * CC;
    u16* Kr   = Qr   + (size_t)MM * CC;
    u16* Vt   = Kr   + (size_t)MM * CC;

    const int ncv = (MM * CC + FF * CC + CC * CC) / 8;
    k_cvt3<<<(ncv + 255) / 256, 256, 0, stream>>>(x, w_qkv, w_out, xb);

    // gemm0 with fused RoPE/split/V^T epilogue (k_rope eliminated)
    k_gemm<2><<<dim3(FF / 128, MM / 128), 256, 0, stream>>>(
        xb, wqb, nullptr, freqs, Qr, Kr, Vt, MM, FF, CC);
    k_attn<<<dim3(8, HH, BB), 256, 0, stream>>>(Qr, Kr, Vt, AO);
    k_gemm<1><<<dim3(CC / 128, MM / 128), 256, 0, stream>>>(
        AO, wob, out, nullptr, nullptr, nullptr, nullptr, MM, CC, CC);
}

// Round 19
// 484.520 us; speedup vs baseline: 1.1391x; 1.0051x over previous
//
#include <hip/hip_runtime.h>

typedef unsigned short u16;
typedef unsigned int   u32;

using sx8   = __attribute__((ext_vector_type(8))) short;   // 8 x bf16 bits
using f32x4 = __attribute__((ext_vector_type(4))) float;
using u16x8 = __attribute__((ext_vector_type(8))) unsigned short;

#define BB 4
#define TT 2048
#define CC 2048
#define HH 16
#define DD 128
#define FF 6144
#define MM 8192

static __device__ __forceinline__ u16 f2bf(float f) {
    u32 u = __builtin_bit_cast(u32, f);
    u32 lsb = (u >> 16) & 1u;
    u += 0x7fffu + lsb;
    return (u16)(u >> 16);
}
static __device__ __forceinline__ float bf2f(u16 b) {
    return __builtin_bit_cast(float, (u32)b << 16);
}
static __device__ __forceinline__ f32x4 mfma16(sx8 a, sx8 b, f32x4 c) {
    return __builtin_amdgcn_mfma_f32_16x16x32_bf16(a, b, c, 0, 0, 0);
}
static __device__ __forceinline__ u32 pkbf(float a, float b) {
    return (u32)f2bf(a) | ((u32)f2bf(b) << 16);
}

// ---------------- fused f32 -> bf16 convert for x, w_qkv, w_out ----------------
__global__ __launch_bounds__(256) void k_cvt3(const float* __restrict__ x,
                                              const float* __restrict__ wq,
                                              const float* __restrict__ wo,
                                              u16* __restrict__ dst) {
    const size_t n0 = (size_t)MM * CC / 8, n1 = n0 + (size_t)FF * CC / 8;
    const size_t n2 = n1 + (size_t)CC * CC / 8;
    size_t i = (size_t)blockIdx.x * 256 + threadIdx.x;
    if (i >= n2) return;
    const float* s;
    size_t off;
    if (i < n0)      { s = x;  off = i; }
    else if (i < n1) { s = wq; off = i - n0; }
    else             { s = wo; off = i - n1; }
    const float4* sp = (const float4*)s;
    float4 a = sp[2 * off], b = sp[2 * off + 1];
    u16x8 r;
    r[0] = f2bf(a.x); r[1] = f2bf(a.y); r[2] = f2bf(a.z); r[3] = f2bf(a.w);
    r[4] = f2bf(b.x); r[5] = f2bf(b.y); r[6] = f2bf(b.z); r[7] = f2bf(b.w);
    *(u16x8*)(dst + 8 * i) = r;
}

// ---------------- bf16 A(MxK) @ Bt(NxK)^T GEMM, m97 structure, BK=128 ----------------
// 128x128 tile, BK=128 (16 iters: half the barrier/drain count of BK=64 — the
// verified lever: T = a + b*iters, a~170us b~1.47us from rounds 15/16).
// Both-sides granule XOR swizzle (g ^= row&7): same bank distribution as the
// measured-conflict-free BK=64 pattern. Staging: 16 GLL/thread/iter via
// even/odd row-quad pointer pairs, linear LDS dest.
// MODE 1: plain f32 C output (out-proj).
// MODE 2: fused epilogue — RoPE(Q,K) + QKV split + V transpose.
template <int MODE>
__global__ __launch_bounds__(256, 2) void k_gemm(const u16* __restrict__ A,
                                                 const u16* __restrict__ Bt,
                                                 float* __restrict__ Cf,
                                                 const float* __restrict__ freqs,
                                                 u16* __restrict__ Qo,
                                                 u16* __restrict__ Ko,
                                                 u16* __restrict__ Vt,
                                                 int M, int N, int K) {
    __shared__ __align__(16) u16 sA[128 * 128];     // 32 KB
    __shared__ __align__(16) u16 sB[128 * 128];     // 32 KB
    __shared__ __align__(16) u16 vT[4][64][17];     // MODE 2 V-transpose staging
    const int n0 = blockIdx.x * 128, m0 = blockIdx.y * 128;
    const int tid = threadIdx.x, w = tid >> 6, l = tid & 63;
    const int wm = w >> 1, wn = w & 1;
    const int lr = l & 15, lg = l >> 4;
    f32x4 acc[4][4] = {};

    // staging: wave w covers rows w*32..w*32+31; 8 calls of 4 rows (1 KB each).
    // call pair c: even rows w*32+8c+lrow4, odd rows w*32+8c+4+lrow4.
    const int lrow4 = l >> 4;                       // 0..3
    const int lg16  = l & 15;
    const int sge = lg16 ^ lrow4;                   // pre-swizzled source granule (even)
    const int sgo = lg16 ^ (4 + lrow4);             // (odd)
    const u16* AsE = A  + (size_t)(m0 + w * 32 + lrow4)     * K + sge * 8;
    const u16* AsO = A  + (size_t)(m0 + w * 32 + 4 + lrow4) * K + sgo * 8;
    const u16* BsE = Bt + (size_t)(n0 + w * 32 + lrow4)     * K + sge * 8;
    const u16* BsO = Bt + (size_t)(n0 + w * 32 + 4 + lrow4) * K + sgo * 8;
    const size_t r8 = (size_t)8 * K;                // 8-row source step per call pair
    u16* dA = sA + w * 4096;                        // wave chunk (8 calls x 512 u16)
    u16* dB = sB + w * 4096;

    const int rx = lr & 7;                          // read-row & 7

    for (int k0 = 0; k0 < K; k0 += 128) {
#pragma unroll
        for (int c = 0; c < 4; ++c) {
            __builtin_amdgcn_global_load_lds(
                (const __attribute__((address_space(1))) void*)(AsE + (size_t)c * r8 + k0),
                (__attribute__((address_space(3))) void*)(dA + (2 * c) * 512), 16, 0, 0);
            __builtin_amdgcn_global_load_lds(
                (const __attribute__((address_space(1))) void*)(AsO + (size_t)c * r8 + k0),
                (__attribute__((address_space(3))) void*)(dA + (2 * c + 1) * 512), 16, 0, 0);
            __builtin_amdgcn_global_load_lds(
                (const __attribute__((address_space(1))) void*)(BsE + (size_t)c * r8 + k0),
                (__attribute__((address_space(3))) void*)(dB + (2 * c) * 512), 16, 0, 0);
            __builtin_amdgcn_global_load_lds(
                (const __attribute__((address_space(1))) void*)(BsO + (size_t)c * r8 + k0),
                (__attribute__((address_space(3))) void*)(dB + (2 * c + 1) * 512), 16, 0, 0);
        }
        __syncthreads();
#pragma unroll
        for (int ks = 0; ks < 4; ++ks) {
            const int g = ((ks * 4 + lg) ^ rx) * 8;
            sx8 af[4], bfr[4];
#pragma unroll
            for (int i = 0; i < 4; i++)
                af[i] = *(const sx8*)(sA + (wm * 64 + i * 16 + lr) * 128 + g);
#pragma unroll
            for (int j = 0; j < 4; j++)
                bfr[j] = *(const sx8*)(sB + (wn * 64 + j * 16 + lr) * 128 + g);
#pragma unroll
            for (int i = 0; i < 4; i++)
#pragma unroll
                for (int j = 0; j < 4; j++)
                    acc[i][j] = mfma16(af[i], bfr[j], acc[i][j]);
        }
        __syncthreads();
    }

    if (MODE == 1) {
        // plain f32 epilogue: D row = (lane>>4)*4+reg, col = lane&15
#pragma unroll
        for (int i = 0; i < 4; i++) {
            const int mr = m0 + wm * 64 + i * 16 + lg * 4;
#pragma unroll
            for (int j = 0; j < 4; j++) {
                const int nc = n0 + wn * 64 + j * 16 + lr;
#pragma unroll
                for (int rg = 0; rg < 4; rg++)
                    Cf[(size_t)(mr + rg) * N + nc] = acc[i][j][rg];
            }
        }
    } else {
        // fused qkv epilogue
        const int b = m0 >> 11;                 // batch (block-uniform)
        const int t0blk = m0 & 2047;
        const int kind = n0 >> 11;              // 0=Q 1=K 2=V (block-uniform)
        const int h = (n0 & 2047) >> 7;         // head (block-uniform)
        const size_t bh = (size_t)(b * HH + h);
        if (kind < 2) {
            u16* dst = (kind == 0 ? Qo : Ko) + bh * (size_t)(TT * DD);
            const float qs = (kind == 0) ? 0.08838834764831845f : 1.0f;
#pragma unroll
            for (int i = 0; i < 4; i++) {
#pragma unroll
                for (int j = 0; j < 4; j++) {
                    const int d = wn * 64 + j * 16 + lr;       // 0..127
                    const int dp2 = (d >> 1) * 2;
#pragma unroll
                    for (int rg = 0; rg < 4; rg++) {
                        const int t = t0blk + wm * 64 + i * 16 + lg * 4 + rg;
                        float v = acc[i][j][rg];
                        float p = __shfl_xor(v, 1);
                        float2 cs = *(const float2*)(freqs + (size_t)t * DD + dp2);
                        float r = (lr & 1) ? (p * cs.y + v * cs.x)
                                           : (v * cs.x - p * cs.y);
                        dst[(size_t)t * DD + d] = f2bf(r * qs);
                    }
                }
            }
        } else {
            u16* dstV = Vt + bh * (size_t)(DD * TT);
            const int t0w = t0blk + wm * 64;
            const int dl = l >> 2, seg = l & 3;
#pragma unroll
            for (int j = 0; j < 4; ++j) {
#pragma unroll
                for (int i = 0; i < 4; ++i)
#pragma unroll
                    for (int rg = 0; rg < 4; ++rg)
                        vT[w][i * 16 + lg * 4 + rg][lr] = f2bf(acc[i][j][rg]);
                asm volatile("s_waitcnt lgkmcnt(0)" ::: "memory");
                __builtin_amdgcn_sched_barrier(0);
                u16x8 t2[2];
#pragma unroll
                for (int jj = 0; jj < 16; ++jj)
                    t2[jj >> 3][jj & 7] = vT[w][seg * 16 + jj][dl];
                const int dg = wn * 64 + j * 16 + dl;
                u16* orow = dstV + (size_t)dg * TT + t0w + seg * 16;
                *(u16x8*)orow = t2[0];
                *((u16x8*)orow + 1) = t2[1];
                asm volatile("s_waitcnt lgkmcnt(0)" ::: "memory");   // reads done before next j overwrites
                __builtin_amdgcn_sched_barrier(0);
            }
        }
    }
}

// ---------------- causal flash attention: 4 waves x 32 q-rows, KVBLK=64 ----------------
// Round-5 schedule (512 uniform blocks, strip-pair (x,15-x), 2-phase dbuf K staging)
// + swapped QK^T: S^T = mfma(K,Q) puts each q-row's scores lane-local
//   (row = lane&15, 16 k-vals in regs) -> in-reg reduce + 2 shfl_xor, packed b64 P writes.
#define KV 64
#define PST 68

__global__ __launch_bounds__(256, 2) void k_attn(const u16* __restrict__ Q,
                                                 const u16* __restrict__ K,
                                                 const u16* __restrict__ Vt,
                                                 u16* __restrict__ AO) {
    const int fid = blockIdx.x + 8 * blockIdx.y + 128 * blockIdx.z;
    const int xg = fid >> 6;                // 0..7  (strip-pair index)
    const int hb = fid & 63;
    const int h = hb & 15, b = hb >> 4;

    const int tid = threadIdx.x, w = tid >> 6, l = tid & 63;
    const int lr = l & 15, lg = l >> 4;
    const size_t bh = (size_t)(b * HH + h);
    const u16* Qh = Q + bh * TT * DD;
    const u16* Kh = K + bh * TT * DD;
    const u16* Vh = Vt + bh * DD * TT;

    __shared__ __align__(16) u16 sK[2][KV * DD];    // 32 KB, double-buffered, XOR-swizzled
    __shared__ __align__(16) u16 sP[4][32 * PST];   // 17 KB, per-wave P tiles
    u16* myP = sP[w];

    const int strow = tid >> 4;       // staging sub-row 0..15
    const int sc16  = tid & 15;       // staging 16B-column

    for (int rep = 0; rep < 2; ++rep) {
        const int g = rep ? (15 - xg) : xg;     // strip-group (128 rows)
        const int q0w = g * 128 + w * 32;       // this wave's first q row
        const int nt = 2 * g + 2;               // k-tiles of 64

        sx8 qf[2][4];
#pragma unroll
        for (int i = 0; i < 2; i++)
#pragma unroll
            for (int kk = 0; kk < 4; kk++)
                qf[i][kk] = *(const sx8*)(Qh + (size_t)(q0w + i * 16 + lr) * DD + kk * 32 + lg * 8);

        f32x4 o[2][8] = {};
        float mrow[2] = {-1e30f, -1e30f};
        float lrow[2] = {0.0f, 0.0f};

        // prologue: stage tile 0 into buf 0 (linear dest, inverse-swizzled source)
#pragma unroll
        for (int i = 0; i < 4; ++i) {
            const int row = i * 16 + strow;
            const int scol = (sc16 ^ (row & 7)) * 8;
            __builtin_amdgcn_global_load_lds(
                (const __attribute__((address_space(1))) void*)(Kh + (size_t)row * DD + scol),
                (__attribute__((address_space(3))) void*)(&sK[0][i * 2048 + w * 512]),
                16, 0, 0);
        }
        __syncthreads();

        int cur = 0;
        for (int t = 0; t < nt; ++t) {
            const int k0 = t * KV;
            if (t + 1 < nt) {               // prefetch next K tile into buf^1
                const int kn = k0 + KV;
#pragma unroll
                for (int i = 0; i < 4; ++i) {
                    const int row = i * 16 + strow;
                    const int scol = (sc16 ^ (row & 7)) * 8;
                    __builtin_amdgcn_global_load_lds(
                        (const __attribute__((address_space(1))) void*)(Kh + (size_t)(kn + row) * DD + scol),
                        (__attribute__((address_space(3))) void*)(&sK[cur ^ 1][i * 2048 + w * 512]),
                        16, 0, 0);
                }
            }
            if (k0 <= q0w) {                // causally active for this wave
                // ---- S^T = K·Q^T from swizzled LDS: k on (lg,rg), q-row on lr ----
                f32x4 st[2][4] = {};
#pragma unroll
                for (int j = 0; j < 4; ++j) {
                    const int row = j * 16 + lr;
                    const int rxk = row & 7;
                    sx8 kf[4];
#pragma unroll
                    for (int kk = 0; kk < 4; ++kk) {
                        const int c16 = (kk * 4 + lg) ^ rxk;
                        kf[kk] = *(const sx8*)(&sK[cur][row * DD + c16 * 8]);
                    }
#pragma unroll
                    for (int kk = 0; kk < 4; ++kk) {
                        st[0][j] = mfma16(kf[kk], qf[0][kk], st[0][j]);
                        st[1][j] = mfma16(kf[kk], qf[1][kk], st[1][j]);
                    }
                }
                // ---- issue first-half V loads early (latency hides under softmax) ----
                sx8 vf0[8];
#pragma unroll
                for (int n = 0; n < 8; ++n)
                    vf0[n] = *(const sx8*)(Vh + (size_t)(n * 16 + lr) * TT + k0 + lg * 8);

                // ---- softmax: q-row lane-local; in-reg tree + 2 shfl_xor ----
                const bool need_mask = (k0 + 63 > q0w);
                const int klocal = lg * 4;          // this lane's k-subcolumn base
#pragma unroll
                for (int i = 0; i < 2; ++i) {
                    if (need_mask) {
                        const int cl = q0w + i * 16 + lr - k0;   // max allowed k-local
#pragma unroll
                        for (int j = 0; j < 4; ++j)
#pragma unroll
                            for (int rg = 0; rg < 4; ++rg)
                                if (j * 16 + klocal + rg > cl) st[i][j][rg] = -1e30f;
                    }
                    f32x4 m4;
#pragma unroll
                    for (int rg = 0; rg < 4; ++rg)
                        m4[rg] = fmaxf(fmaxf(st[i][0][rg], st[i][1][rg]),
                                       fmaxf(st[i][2][rg], st[i][3][rg]));
                    float pm = fmaxf(fmaxf(m4[0], m4[1]), fmaxf(m4[2], m4[3]));
                    pm = fmaxf(pm, __shfl_xor(pm, 16));
                    pm = fmaxf(pm, __shfl_xor(pm, 32));
                    const float mold = mrow[i];
                    const bool resc = pm > mold + 8.0f;     // defer-max (T13)
                    const float mnew = resc ? pm : mold;
                    mrow[i] = mnew;
                    float rs = 0.0f;
#pragma unroll
                    for (int j = 0; j < 4; ++j) {
                        float p0 = __expf(st[i][j][0] - mnew);
                        float p1 = __expf(st[i][j][1] - mnew);
                        float p2 = __expf(st[i][j][2] - mnew);
                        float p3 = __expf(st[i][j][3] - mnew);
                        rs += (p0 + p1) + (p2 + p3);
                        *(uint2*)(myP + (i * 16 + lr) * PST + j * 16 + klocal) =
                            make_uint2(pkbf(p0, p1), pkbf(p2, p3));
                    }
                    rs += __shfl_xor(rs, 16);
                    rs += __shfl_xor(rs, 32);
                    const float sf = resc ? __expf(mold - mnew) : 1.0f;
                    lrow[i] = lrow[i] * sf + rs;
                    if (__any(resc)) {                       // rare with defer-max
                        f32x4 sfo;
#pragma unroll
                        for (int rg = 0; rg < 4; ++rg)
                            sfo[rg] = __shfl(sf, 4 * lg + rg);
#pragma unroll
                        for (int n = 0; n < 8; ++n) o[i][n] *= sfo;
                    }
                }
                // ensure P writes landed before cross-lane reads (per-wave region)
                asm volatile("s_waitcnt lgkmcnt(0)" ::: "memory");
                __builtin_amdgcn_sched_barrier(0);

                // ---- PV: P as A-operand, V^T as B-operand ----
                sx8 pa0[2], pa1[2];
                pa0[0] = *(const sx8*)(myP + (size_t)lr * PST + lg * 8);
                pa0[1] = *(const sx8*)(myP + (size_t)(16 + lr) * PST + lg * 8);
                pa1[0] = *(const sx8*)(myP + (size_t)lr * PST + 32 + lg * 8);
                pa1[1] = *(const sx8*)(myP + (size_t)(16 + lr) * PST + 32 + lg * 8);
#pragma unroll
                for (int n = 0; n < 8; ++n) {
                    o[0][n] = mfma16(pa0[0], vf0[n], o[0][n]);
                    o[1][n] = mfma16(pa0[1], vf0[n], o[1][n]);
                }
#pragma unroll
                for (int n = 0; n < 8; ++n) {
                    sx8 vf1 = *(const sx8*)(Vh + (size_t)(n * 16 + lr) * TT + k0 + 32 + lg * 8);
                    o[0][n] = mfma16(pa1[0], vf1, o[0][n]);
                    o[1][n] = mfma16(pa1[1], vf1, o[1][n]);
                }
            }
            __syncthreads();    // drains vmcnt (prefetch done) + all waves done with sK[cur]
            cur ^= 1;
        }

        // ---- epilogue: fetch l for this lane's O-rows, write strip ----
#pragma unroll
        for (int i = 0; i < 2; ++i) {
            f32x4 linv;
#pragma unroll
            for (int rg = 0; rg < 4; ++rg)
                linv[rg] = __shfl(lrow[i], 4 * lg + rg);
#pragma unroll
            for (int rg = 0; rg < 4; ++rg) {
                const float inv = 1.0f / linv[rg];
                const int tq = q0w + i * 16 + lg * 4 + rg;
                u16* orow = AO + ((size_t)(b * TT) + tq) * CC + h * DD + lr;
#pragma unroll
                for (int n = 0; n < 8; ++n)
                    orow[n * 16] = f2bf(o[i][n][rg] * inv);
            }
        }
    }
}

extern "C" void kernel_launch(void* const* d_in, const int* in_sizes, int n_in,
                              void* d_out, int out_size, void* d_ws, size_t ws_size,
                              hipStream_t stream) {
    const float* x     = (const float*)d_in[0];
    const float* freqs = (const float*)d_in[1];
    // d_in[2] = mask: causal, implemented analytically
    const float* w_qkv = (const float*)d_in[3];
    const float* w_out = (const float*)d_in[4];
    float* out = (float*)d_out;

    u16* ws   = (u16*)d_ws;
    u16* xb   = ws;
    u16* wqb  = xb   + (size_t)MM * CC;
    u16* wob  = wqb  + (size_t)FF * CC;
    u16* AO   = wob  + (size_t)CC * CC;      // attn output (b,t,h*d)
    u16* Qr   = AO   + (size_t)MM * CC;
    u16* Kr   = Qr   + (size_t)MM * CC;
    u16* Vt   = Kr   + (size_t)MM * CC;

    const int ncv = (MM * CC + FF * CC + CC * CC) / 8;
    k_cvt3<<<(ncv + 255) / 256, 256, 0, stream>>>(x, w_qkv, w_out, xb);

    // gemm0 with fused RoPE/split/V^T epilogue (k_rope eliminated)
    k_gemm<2><<<dim3(FF / 128, MM / 128), 256, 0, stream>>>(
        xb, wqb, nullptr, freqs, Qr, Kr, Vt, MM, FF, CC);
    k_attn<<<dim3(8, HH, BB), 256, 0, stream>>>(Qr, Kr, Vt, AO);
    k_gemm<1><<<dim3(CC / 128, MM / 128), 256, 0, stream>>>(
        AO, wob, out, nullptr, nullptr, nullptr, nullptr, MM, CC, CC);
}